// Round 1
// baseline (94.365 us; speedup 1.0000x reference)
//
#include <hip/hip_runtime.h>

// PTS loss: B=32 batches, N=2048 points.
//   non-sym batch: sum_n ||R_e p_n - R_g p_n||^2
//   sym batch:     sum_n min_m ||R_e p_n - R_g p_m||^2   (chamfer-style NN)
// Scalar out = (sum_s + sum_p) / (2*N*B).
// Strategy: one x-point per thread, block stages all rotated gt points (+|y|^2)
// in LDS; inner loop = 1 broadcast ds_read_b128 + 3 fma + 1 min per candidate.

#define TPB   256
#define NPTS  2048
#define SPLIT (NPTS / TPB)   // 8 blocks per batch

__device__ __forceinline__ void quat2mat(const float* __restrict__ q, float R[9]) {
    float w = q[0], x = q[1], y = q[2], z = q[3];
    float inv = 1.0f / sqrtf(w*w + x*x + y*y + z*z);
    w *= inv; x *= inv; y *= inv; z *= inv;
    R[0] = 1.f - 2.f*(y*y + z*z); R[1] = 2.f*(x*y - w*z);       R[2] = 2.f*(x*z + w*y);
    R[3] = 2.f*(x*y + w*z);       R[4] = 1.f - 2.f*(x*x + z*z); R[5] = 2.f*(y*z - w*x);
    R[6] = 2.f*(x*z - w*y);       R[7] = 2.f*(y*z + w*x);       R[8] = 1.f - 2.f*(x*x + y*y);
}

__global__ __launch_bounds__(TPB) void pts_loss_kernel(
    const float* __restrict__ q_est, const float* __restrict__ q_gt,
    const float* __restrict__ pts, const int* __restrict__ symmetries,
    float* __restrict__ out, float scale)
{
    const int split = blockIdx.x;
    const int b     = blockIdx.y;
    const int tid   = threadIdx.x;

    __shared__ float  raw[NPTS * 3];   // staged raw pts (24 KB)
    __shared__ float4 ybuf[NPTS];      // y0,y1,y2,|y|^2 (32 KB)
    __shared__ float  red[TPB / 64];

    float Re[9], Rg[9];
    quat2mat(q_est + 4 * b, Re);
    quat2mat(q_gt  + 4 * b, Rg);

    const float* pb = pts + (size_t)b * NPTS * 3;
    const bool is_sym = symmetries[b] != 0;  // block-uniform branch
    const int  n = split * TPB + tid;

    float partial;

    if (is_sym) {
        // stage raw pts coalesced
        for (int i = tid; i < NPTS * 3; i += TPB) raw[i] = pb[i];
        __syncthreads();
        // rotate gt points into ybuf with precomputed |y|^2
        for (int m = tid; m < NPTS; m += TPB) {
            float p0 = raw[3*m+0], p1 = raw[3*m+1], p2 = raw[3*m+2];
            float y0 = Rg[0]*p0 + Rg[1]*p1 + Rg[2]*p2;
            float y1 = Rg[3]*p0 + Rg[4]*p1 + Rg[5]*p2;
            float y2 = Rg[6]*p0 + Rg[7]*p1 + Rg[8]*p2;
            ybuf[m] = make_float4(y0, y1, y2, y0*y0 + y1*y1 + y2*y2);
        }
        __syncthreads();

        // my est point
        float p0 = raw[3*n+0], p1 = raw[3*n+1], p2 = raw[3*n+2];
        float x0 = Re[0]*p0 + Re[1]*p1 + Re[2]*p2;
        float x1 = Re[3]*p0 + Re[4]*p1 + Re[5]*p2;
        float x2 = Re[6]*p0 + Re[7]*p1 + Re[8]*p2;
        float xx  = x0*x0 + x1*x1 + x2*x2;
        float nx0 = -2.f*x0, nx1 = -2.f*x1, nx2 = -2.f*x2;

        // min_m (|y|^2 - 2 x.y); add xx after the loop
        float m0 = 1e30f, m1 = 1e30f, m2 = 1e30f, m3 = 1e30f;
        #pragma unroll 2
        for (int m = 0; m < NPTS; m += 4) {
            float4 ya = ybuf[m+0];
            float4 yb = ybuf[m+1];
            float4 yc = ybuf[m+2];
            float4 yd = ybuf[m+3];
            float t0 = fmaf(nx0, ya.x, fmaf(nx1, ya.y, fmaf(nx2, ya.z, ya.w)));
            float t1 = fmaf(nx0, yb.x, fmaf(nx1, yb.y, fmaf(nx2, yb.z, yb.w)));
            float t2 = fmaf(nx0, yc.x, fmaf(nx1, yc.y, fmaf(nx2, yc.z, yc.w)));
            float t3 = fmaf(nx0, yd.x, fmaf(nx1, yd.y, fmaf(nx2, yd.z, yd.w)));
            m0 = fminf(m0, t0); m1 = fminf(m1, t1);
            m2 = fminf(m2, t2); m3 = fminf(m3, t3);
        }
        partial = fminf(fminf(m0, m1), fminf(m2, m3)) + xx;
    } else {
        // d_p path: direct per-point squared distance, no LDS needed
        float p0 = pb[3*n+0], p1 = pb[3*n+1], p2 = pb[3*n+2];
        float e0 = Re[0]*p0 + Re[1]*p1 + Re[2]*p2;
        float e1 = Re[3]*p0 + Re[4]*p1 + Re[5]*p2;
        float e2 = Re[6]*p0 + Re[7]*p1 + Re[8]*p2;
        float g0 = Rg[0]*p0 + Rg[1]*p1 + Rg[2]*p2;
        float g1 = Rg[3]*p0 + Rg[4]*p1 + Rg[5]*p2;
        float g2 = Rg[6]*p0 + Rg[7]*p1 + Rg[8]*p2;
        float d0 = e0 - g0, d1 = e1 - g1, d2 = e2 - g2;
        partial = d0*d0 + d1*d1 + d2*d2;
    }

    // wave64 reduce
    #pragma unroll
    for (int off = 32; off > 0; off >>= 1)
        partial += __shfl_down(partial, off, 64);
    if ((tid & 63) == 0) red[tid >> 6] = partial;
    __syncthreads();
    if (tid == 0) {
        float tot = red[0] + red[1] + red[2] + red[3];
        atomicAdd(out, tot * scale);
    }
}

extern "C" void kernel_launch(void* const* d_in, const int* in_sizes, int n_in,
                              void* d_out, int out_size, void* d_ws, size_t ws_size,
                              hipStream_t stream) {
    const float* q_est = (const float*)d_in[0];
    const float* q_gt  = (const float*)d_in[1];
    // d_in[2] = T, unused by the reference
    const float* pts   = (const float*)d_in[3];
    const int*   sym   = (const int*)d_in[4];
    float* out = (float*)d_out;

    const int B = in_sizes[0] / 4;           // 32
    const float scale = 1.0f / (2.0f * (float)NPTS * (float)B);

    hipMemsetAsync(out, 0, sizeof(float), stream);
    dim3 grid(SPLIT, B);
    pts_loss_kernel<<<grid, TPB, 0, stream>>>(q_est, q_gt, pts, sym, out, scale);
}

// Round 2
// 85.356 us; speedup vs baseline: 1.1056x; 1.1056x over previous
//
#include <hip/hip_runtime.h>

// PTS loss: B=32, N=2048.
//   non-sym batch: sum_n ||R_e p_n - R_g p_n||^2
//   sym batch:     sum_n min_m ||R_e p_n - R_g p_m||^2
// out = (sum_s + sum_p) / (2*N*B), single f32 scalar.
//
// R2 structure: kernel A = grid (B=32, MS=8). Sym block (b,ms) stages a
// 256-candidate y-chunk (rotated gt + |y|^2) in LDS; each thread owns PX=8
// x-points, so one broadcast ds_read_b128 feeds 32 VALU ops (8x fewer LDS
// instructions than R1, VALU-bound). Partial mins (without xx) go to ws;
// kernel B mins over the 8 chunks, adds xx, reduces, atomicAdds the scalar.
// Non-sym batches: ms==0 block computes d_p directly and atomicAdds.

#define TPB  256
#define NPTS 2048
#define MS   8            // m-chunks per sym batch
#define MCH  (NPTS / MS)  // 256 candidates per chunk
#define PX   8            // x-points per thread (NPTS / TPB)

__device__ __forceinline__ void quat2mat(const float* __restrict__ q, float R[9]) {
    float w = q[0], x = q[1], y = q[2], z = q[3];
    float inv = 1.0f / sqrtf(w*w + x*x + y*y + z*z);
    w *= inv; x *= inv; y *= inv; z *= inv;
    R[0] = 1.f - 2.f*(y*y + z*z); R[1] = 2.f*(x*y - w*z);       R[2] = 2.f*(x*z + w*y);
    R[3] = 2.f*(x*y + w*z);       R[4] = 1.f - 2.f*(x*x + z*z); R[5] = 2.f*(y*z - w*x);
    R[6] = 2.f*(x*z - w*y);       R[7] = 2.f*(y*z + w*x);       R[8] = 1.f - 2.f*(x*x + y*y);
}

__device__ __forceinline__ float block_reduce_add(float v, float* red) {
    #pragma unroll
    for (int off = 32; off > 0; off >>= 1)
        v += __shfl_down(v, off, 64);
    const int tid = threadIdx.x;
    if ((tid & 63) == 0) red[tid >> 6] = v;
    __syncthreads();
    return red[0] + red[1] + red[2] + red[3];
}

__global__ __launch_bounds__(TPB) void pts_loss_A(
    const float* __restrict__ q_est, const float* __restrict__ q_gt,
    const float* __restrict__ pts, const int* __restrict__ symmetries,
    float* __restrict__ out, float* __restrict__ partial, float* __restrict__ xx_ws,
    float scale)
{
    const int b   = blockIdx.x;
    const int ms  = blockIdx.y;
    const int tid = threadIdx.x;

    __shared__ float4 ybuf[MCH];      // 4 KB
    __shared__ float  red[TPB / 64];

    const bool is_sym = symmetries[b] != 0;   // block-uniform
    const float* pb = pts + (size_t)b * NPTS * 3;

    if (!is_sym) {
        if (ms != 0) return;
        float Re[9], Rg[9];
        quat2mat(q_est + 4*b, Re);
        quat2mat(q_gt  + 4*b, Rg);
        float s = 0.f;
        #pragma unroll
        for (int k = 0; k < PX; ++k) {
            int n = k * TPB + tid;
            float p0 = pb[3*n+0], p1 = pb[3*n+1], p2 = pb[3*n+2];
            float d0 = (Re[0]-Rg[0])*p0 + (Re[1]-Rg[1])*p1 + (Re[2]-Rg[2])*p2;
            float d1 = (Re[3]-Rg[3])*p0 + (Re[4]-Rg[4])*p1 + (Re[5]-Rg[5])*p2;
            float d2 = (Re[6]-Rg[6])*p0 + (Re[7]-Rg[7])*p1 + (Re[8]-Rg[8])*p2;
            s += d0*d0 + d1*d1 + d2*d2;
        }
        s = block_reduce_add(s, red);
        if (tid == 0) atomicAdd(out, s * scale);
        return;
    }

    float Re[9], Rg[9];
    quat2mat(q_est + 4*b, Re);
    quat2mat(q_gt  + 4*b, Rg);

    // stage this block's y-chunk: candidate m = ms*MCH + tid
    {
        int m = ms * MCH + tid;
        float p0 = pb[3*m+0], p1 = pb[3*m+1], p2 = pb[3*m+2];
        float y0 = Rg[0]*p0 + Rg[1]*p1 + Rg[2]*p2;
        float y1 = Rg[3]*p0 + Rg[4]*p1 + Rg[5]*p2;
        float y2 = Rg[6]*p0 + Rg[7]*p1 + Rg[8]*p2;
        ybuf[tid] = make_float4(y0, y1, y2, y0*y0 + y1*y1 + y2*y2);
    }
    __syncthreads();

    // my PX x-points: n = k*TPB + tid (coalesced)
    float nx0[PX], nx1[PX], nx2[PX], mins[PX];
    #pragma unroll
    for (int k = 0; k < PX; ++k) {
        int n = k * TPB + tid;
        float p0 = pb[3*n+0], p1 = pb[3*n+1], p2 = pb[3*n+2];
        float x0 = Re[0]*p0 + Re[1]*p1 + Re[2]*p2;
        float x1 = Re[3]*p0 + Re[4]*p1 + Re[5]*p2;
        float x2 = Re[6]*p0 + Re[7]*p1 + Re[8]*p2;
        nx0[k] = -2.f*x0; nx1[k] = -2.f*x1; nx2[k] = -2.f*x2;
        mins[k] = 1e30f;
        if (ms == 0) xx_ws[(size_t)b * NPTS + n] = x0*x0 + x1*x1 + x2*x2;
    }

    // min over this chunk: one broadcast b128 read feeds 8 points (32 VALU)
    #pragma unroll 4
    for (int m = 0; m < MCH; ++m) {
        float4 y = ybuf[m];
        #pragma unroll
        for (int k = 0; k < PX; ++k) {
            float t = fmaf(nx0[k], y.x, fmaf(nx1[k], y.y, fmaf(nx2[k], y.z, y.w)));
            mins[k] = fminf(mins[k], t);
        }
    }

    float* pp = partial + ((size_t)b * MS + ms) * NPTS;
    #pragma unroll
    for (int k = 0; k < PX; ++k)
        pp[k * TPB + tid] = mins[k];
}

__global__ __launch_bounds__(TPB) void pts_loss_B(
    const int* __restrict__ symmetries,
    const float* __restrict__ partial, const float* __restrict__ xx_ws,
    float* __restrict__ out, float scale)
{
    const int b   = blockIdx.x;
    const int tid = threadIdx.x;
    __shared__ float red[TPB / 64];

    if (symmetries[b] == 0) return;

    const float* pb = partial + (size_t)b * MS * NPTS;
    const float* xb = xx_ws + (size_t)b * NPTS;
    float s = 0.f;
    #pragma unroll
    for (int k = 0; k < PX; ++k) {
        int n = k * TPB + tid;
        float v = pb[n];
        #pragma unroll
        for (int ms = 1; ms < MS; ++ms)
            v = fminf(v, pb[ms * NPTS + n]);
        s += v + xb[n];
    }
    s = block_reduce_add(s, red);
    if (tid == 0) atomicAdd(out, s * scale);
}

extern "C" void kernel_launch(void* const* d_in, const int* in_sizes, int n_in,
                              void* d_out, int out_size, void* d_ws, size_t ws_size,
                              hipStream_t stream) {
    const float* q_est = (const float*)d_in[0];
    const float* q_gt  = (const float*)d_in[1];
    // d_in[2] = T, unused by the reference
    const float* pts   = (const float*)d_in[3];
    const int*   sym   = (const int*)d_in[4];
    float* out = (float*)d_out;

    const int B = in_sizes[0] / 4;  // 32
    const float scale = 1.0f / (2.0f * (float)NPTS * (float)B);

    float* partial = (float*)d_ws;                              // B*MS*NPTS = 2 MB
    float* xx_ws   = partial + (size_t)B * MS * NPTS;           // B*NPTS = 256 KB

    hipMemsetAsync(out, 0, sizeof(float), stream);
    dim3 gridA(B, MS);
    pts_loss_A<<<gridA, TPB, 0, stream>>>(q_est, q_gt, pts, sym, out, partial, xx_ws, scale);
    pts_loss_B<<<B, TPB, 0, stream>>>(sym, partial, xx_ws, out, scale);
}

// Round 3
// 76.554 us; speedup vs baseline: 1.2327x; 1.1150x over previous
//
#include <hip/hip_runtime.h>

// PTS loss: B=32, N=2048.
//   non-sym batch: sum_n ||R_e p_n - R_g p_n||^2
//   sym batch:     sum_n min_m ||R_e p_n - R_g p_m||^2
// out = (sum_s + sum_p) / (2*N*B), single f32 scalar.
//
// R3: MS=16 m-chunks (A blocks: 128 cand x 8 pts/thread = 4096 VALU ~= 3.4us),
// memset dispatch removed (A block (0,0) zeroes out; B atomicAdds after the
// kernel boundary). Non-sym sums routed through ws so A never atomicAdds out.

#define TPB  256
#define NPTS 2048
#define MS   16           // m-chunks per sym batch
#define MCH  (NPTS / MS)  // 128 candidates per chunk
#define PX   8            // x-points per thread (NPTS / TPB)

__device__ __forceinline__ void quat2mat(const float* __restrict__ q, float R[9]) {
    float w = q[0], x = q[1], y = q[2], z = q[3];
    float inv = 1.0f / sqrtf(w*w + x*x + y*y + z*z);
    w *= inv; x *= inv; y *= inv; z *= inv;
    R[0] = 1.f - 2.f*(y*y + z*z); R[1] = 2.f*(x*y - w*z);       R[2] = 2.f*(x*z + w*y);
    R[3] = 2.f*(x*y + w*z);       R[4] = 1.f - 2.f*(x*x + z*z); R[5] = 2.f*(y*z - w*x);
    R[6] = 2.f*(x*z - w*y);       R[7] = 2.f*(y*z + w*x);       R[8] = 1.f - 2.f*(x*x + y*y);
}

__device__ __forceinline__ float block_reduce_add(float v, float* red) {
    #pragma unroll
    for (int off = 32; off > 0; off >>= 1)
        v += __shfl_down(v, off, 64);
    const int tid = threadIdx.x;
    if ((tid & 63) == 0) red[tid >> 6] = v;
    __syncthreads();
    return red[0] + red[1] + red[2] + red[3];
}

__global__ __launch_bounds__(TPB) void pts_loss_A(
    const float* __restrict__ q_est, const float* __restrict__ q_gt,
    const float* __restrict__ pts, const int* __restrict__ symmetries,
    float* __restrict__ out, float* __restrict__ partial,
    float* __restrict__ xx_ws, float* __restrict__ bsum)
{
    const int b   = blockIdx.x;
    const int ms  = blockIdx.y;
    const int tid = threadIdx.x;

    __shared__ float4 ybuf[MCH];      // 2 KB
    __shared__ float  red[TPB / 64];

    // zero the scalar output: single producer, B reads after kernel boundary
    if (b == 0 && ms == 0 && tid == 0) *out = 0.f;

    const bool is_sym = symmetries[b] != 0;   // block-uniform
    const float* pb = pts + (size_t)b * NPTS * 3;

    if (!is_sym) {
        if (ms != 0) return;
        float Re[9], Rg[9];
        quat2mat(q_est + 4*b, Re);
        quat2mat(q_gt  + 4*b, Rg);
        float s = 0.f;
        #pragma unroll
        for (int k = 0; k < PX; ++k) {
            int n = k * TPB + tid;
            float p0 = pb[3*n+0], p1 = pb[3*n+1], p2 = pb[3*n+2];
            float d0 = (Re[0]-Rg[0])*p0 + (Re[1]-Rg[1])*p1 + (Re[2]-Rg[2])*p2;
            float d1 = (Re[3]-Rg[3])*p0 + (Re[4]-Rg[4])*p1 + (Re[5]-Rg[5])*p2;
            float d2 = (Re[6]-Rg[6])*p0 + (Re[7]-Rg[7])*p1 + (Re[8]-Rg[8])*p2;
            s += d0*d0 + d1*d1 + d2*d2;
        }
        s = block_reduce_add(s, red);
        if (tid == 0) bsum[b] = s;
        return;
    }

    float Re[9], Rg[9];
    quat2mat(q_est + 4*b, Re);
    quat2mat(q_gt  + 4*b, Rg);

    // stage this block's y-chunk: candidate m = ms*MCH + tid  (tid < MCH)
    if (tid < MCH) {
        int m = ms * MCH + tid;
        float p0 = pb[3*m+0], p1 = pb[3*m+1], p2 = pb[3*m+2];
        float y0 = Rg[0]*p0 + Rg[1]*p1 + Rg[2]*p2;
        float y1 = Rg[3]*p0 + Rg[4]*p1 + Rg[5]*p2;
        float y2 = Rg[6]*p0 + Rg[7]*p1 + Rg[8]*p2;
        ybuf[tid] = make_float4(y0, y1, y2, y0*y0 + y1*y1 + y2*y2);
    }
    __syncthreads();

    // my PX x-points: n = k*TPB + tid (coalesced)
    float nx0[PX], nx1[PX], nx2[PX], mins[PX];
    #pragma unroll
    for (int k = 0; k < PX; ++k) {
        int n = k * TPB + tid;
        float p0 = pb[3*n+0], p1 = pb[3*n+1], p2 = pb[3*n+2];
        float x0 = Re[0]*p0 + Re[1]*p1 + Re[2]*p2;
        float x1 = Re[3]*p0 + Re[4]*p1 + Re[5]*p2;
        float x2 = Re[6]*p0 + Re[7]*p1 + Re[8]*p2;
        nx0[k] = -2.f*x0; nx1[k] = -2.f*x1; nx2[k] = -2.f*x2;
        mins[k] = 1e30f;
        if (ms == 0) xx_ws[(size_t)b * NPTS + n] = x0*x0 + x1*x1 + x2*x2;
    }

    // min over this chunk: one broadcast b128 read feeds 8 points (32 VALU)
    #pragma unroll 4
    for (int m = 0; m < MCH; ++m) {
        float4 y = ybuf[m];
        #pragma unroll
        for (int k = 0; k < PX; ++k) {
            float t = fmaf(nx0[k], y.x, fmaf(nx1[k], y.y, fmaf(nx2[k], y.z, y.w)));
            mins[k] = fminf(mins[k], t);
        }
    }

    float* pp = partial + ((size_t)b * MS + ms) * NPTS;
    #pragma unroll
    for (int k = 0; k < PX; ++k)
        pp[k * TPB + tid] = mins[k];
}

__global__ __launch_bounds__(TPB) void pts_loss_B(
    const int* __restrict__ symmetries,
    const float* __restrict__ partial, const float* __restrict__ xx_ws,
    const float* __restrict__ bsum, float* __restrict__ out, float scale)
{
    const int b   = blockIdx.x;
    const int tid = threadIdx.x;
    __shared__ float red[TPB / 64];

    if (symmetries[b] == 0) {
        if (tid == 0) atomicAdd(out, bsum[b] * scale);
        return;
    }

    const float* pb = partial + (size_t)b * MS * NPTS;
    const float* xb = xx_ws + (size_t)b * NPTS;
    float s = 0.f;
    #pragma unroll
    for (int k = 0; k < PX; ++k) {
        int n = k * TPB + tid;
        float v = pb[n];
        #pragma unroll
        for (int ms = 1; ms < MS; ++ms)
            v = fminf(v, pb[ms * NPTS + n]);
        s += v + xb[n];
    }
    s = block_reduce_add(s, red);
    if (tid == 0) atomicAdd(out, s * scale);
}

extern "C" void kernel_launch(void* const* d_in, const int* in_sizes, int n_in,
                              void* d_out, int out_size, void* d_ws, size_t ws_size,
                              hipStream_t stream) {
    const float* q_est = (const float*)d_in[0];
    const float* q_gt  = (const float*)d_in[1];
    // d_in[2] = T, unused by the reference
    const float* pts   = (const float*)d_in[3];
    const int*   sym   = (const int*)d_in[4];
    float* out = (float*)d_out;

    const int B = in_sizes[0] / 4;  // 32
    const float scale = 1.0f / (2.0f * (float)NPTS * (float)B);

    float* partial = (float*)d_ws;                       // B*MS*NPTS = 4 MB
    float* xx_ws   = partial + (size_t)B * MS * NPTS;    // B*NPTS = 256 KB
    float* bsum    = xx_ws + (size_t)B * NPTS;           // B floats

    dim3 gridA(B, MS);
    pts_loss_A<<<gridA, TPB, 0, stream>>>(q_est, q_gt, pts, sym, out, partial, xx_ws, bsum);
    pts_loss_B<<<B, TPB, 0, stream>>>(sym, partial, xx_ws, bsum, out, scale);
}